// Round 1
// baseline (1239.800 us; speedup 1.0000x reference)
//
#include <hip/hip_runtime.h>
#include <math.h>

// GAT 3-layer forward on MI355X. fp32 throughout.
// N=50000 nodes, E=850000 edges (incl self loops), IN=128, HID=OUT=32, HEADS=(4,4,6).

// ---------------- CSR build (by dst) ----------------

__global__ void hist_kernel(const int* __restrict__ dst, int E, int* __restrict__ deg) {
    int i = blockIdx.x * blockDim.x + threadIdx.x;
    if (i < E) atomicAdd(&deg[dst[i]], 1);
}

__global__ void scan_kernel(const int* __restrict__ deg, int* __restrict__ row_start, int n) {
    const int T = 1024;
    __shared__ int sums[T];
    int t = threadIdx.x;
    int chunk = (n + T - 1) / T;
    int begin = t * chunk;
    int finish = begin + chunk; if (finish > n) finish = n;
    int s = 0;
    for (int i = begin; i < finish; i++) s += deg[i];
    sums[t] = s;
    __syncthreads();
    for (int off = 1; off < T; off <<= 1) {
        int u = (t >= off) ? sums[t - off] : 0;
        __syncthreads();
        sums[t] += u;
        __syncthreads();
    }
    int base = (t == 0) ? 0 : sums[t - 1];
    for (int i = begin; i < finish; i++) { row_start[i] = base; base += deg[i]; }
    if (t == T - 1) row_start[n] = sums[T - 1];
}

__global__ void fill_kernel(const int* __restrict__ src, const int* __restrict__ dst, int E,
                            const int* __restrict__ row_start, int* __restrict__ cursor,
                            int* __restrict__ csr_src) {
    int i = blockIdx.x * blockDim.x + threadIdx.x;
    if (i < E) {
        int d = dst[i];
        int pos = atomicAdd(&cursor[d], 1);
        csr_src[row_start[d] + pos] = src[i];
    }
}

// ---------------- fc + attention logits ----------------
// feat[n, 0..M1) = h[n,:] @ W  (K=128); el/er = per-head dot with al/ar.
// If RES: threads [M1, M1+192) compute res_out = h @ Wres (layer 3 fused).
// Block handles ROWS consecutive nodes; one thread per output column.

template <int M1, int H, bool RES, int ROWS>
__global__ void fc_att(const float* __restrict__ h, const float* __restrict__ W,
                       const float* __restrict__ Wres, const float* __restrict__ al,
                       const float* __restrict__ ar, float* __restrict__ feat,
                       float* __restrict__ res_out, float* __restrict__ el,
                       float* __restrict__ er, int N) {
    __shared__ float hrow[ROWS][128];
    int n0 = blockIdx.x * ROWS;
    int t = threadIdx.x;

    for (int i = t; i < ROWS * 128; i += blockDim.x) {
        int r = i >> 7, c = i & 127;
        int nn = n0 + r;
        hrow[r][c] = (nn < N) ? h[(size_t)nn * 128 + c] : 0.f;
    }
    __syncthreads();

    if (t < M1) {
        float acc[ROWS];
        #pragma unroll
        for (int r = 0; r < ROWS; r++) acc[r] = 0.f;
        #pragma unroll 8
        for (int k = 0; k < 128; k++) {
            float w = W[(size_t)k * M1 + t];
            #pragma unroll
            for (int r = 0; r < ROWS; r++) acc[r] += hrow[r][k] * w;
        }
        float alv = al[t], arv = ar[t];
        #pragma unroll
        for (int r = 0; r < ROWS; r++) {
            int nn = n0 + r;
            if (nn >= N) continue;
            feat[(size_t)nn * M1 + t] = acc[r];
            float pl = acc[r] * alv;
            float pr = acc[r] * arv;
            #pragma unroll
            for (int off = 1; off < 32; off <<= 1) {
                pl += __shfl_xor(pl, off);
                pr += __shfl_xor(pr, off);
            }
            if ((t & 31) == 0) {
                el[(size_t)nn * H + (t >> 5)] = pl;
                er[(size_t)nn * H + (t >> 5)] = pr;
            }
        }
    } else if (RES) {
        int j = t - M1;  // < 192
        float acc[ROWS];
        #pragma unroll
        for (int r = 0; r < ROWS; r++) acc[r] = 0.f;
        #pragma unroll 8
        for (int k = 0; k < 128; k++) {
            float w = Wres[(size_t)k * 192 + j];
            #pragma unroll
            for (int r = 0; r < ROWS; r++) acc[r] += hrow[r][k] * w;
        }
        #pragma unroll
        for (int r = 0; r < ROWS; r++) {
            int nn = n0 + r;
            if (nn < N) res_out[(size_t)nn * 192 + j] = acc[r];
        }
    }
}

// ---------------- per-node edge softmax + weighted aggregate ----------------
// One block per node, one wave (64 lanes) per head.
// Pass A: segment max (lanes stride edges). Pass B: denom. Pass C: weighted sum
// (each 32-lane half owns alternate edges; lane owns dim d = lane&31).

template <int H, bool RELU, bool MEAN>
__global__ void gat_agg(const float* __restrict__ feat, const float* __restrict__ el,
                        const float* __restrict__ er, const int* __restrict__ row_start,
                        const int* __restrict__ csr_src, const float* __restrict__ bias,
                        const float* __restrict__ residual, float* __restrict__ out, int N) {
    int n = blockIdx.x;
    int h = threadIdx.x >> 6;
    int lane = threadIdx.x & 63;
    int sub = lane >> 5;
    int d = lane & 31;

    int start = row_start[n];
    int end = row_start[n + 1];
    float er_n = er[(size_t)n * H + h];

    // Pass A: max over incoming edges
    float m = -INFINITY;
    for (int j = start + lane; j < end; j += 64) {
        int s = csr_src[j];
        float e = el[(size_t)s * H + h] + er_n;
        e = (e >= 0.f) ? e : 0.2f * e;
        m = fmaxf(m, e);
    }
    #pragma unroll
    for (int off = 32; off >= 1; off >>= 1) m = fmaxf(m, __shfl_xor(m, off));

    // Pass B: softmax denominator
    float dsum = 0.f;
    for (int j = start + lane; j < end; j += 64) {
        int s = csr_src[j];
        float e = el[(size_t)s * H + h] + er_n;
        e = (e >= 0.f) ? e : 0.2f * e;
        dsum += __expf(e - m);
    }
    #pragma unroll
    for (int off = 32; off >= 1; off >>= 1) dsum += __shfl_xor(dsum, off);

    // Pass C: weighted feature sum
    float acc = 0.f;
    for (int j = start + sub; j < end; j += 2) {
        int s = csr_src[j];
        float e = el[(size_t)s * H + h] + er_n;
        e = (e >= 0.f) ? e : 0.2f * e;
        float w = __expf(e - m);
        acc += w * feat[(size_t)s * (H * 32) + h * 32 + d];
    }
    acc += __shfl_xor(acc, 32);

    float rst = acc / fmaxf(dsum, 1e-9f);
    rst += bias[h * 32 + d];
    if (residual) rst += residual[(size_t)n * (H * 32) + h * 32 + d];
    if (RELU) rst = fmaxf(rst, 0.f);

    if (!MEAN) {
        if (sub == 0) out[(size_t)n * (H * 32) + h * 32 + d] = rst;
    } else {
        __shared__ float sred[H * 32];
        if (sub == 0) sred[h * 32 + d] = rst;
        __syncthreads();
        if (threadIdx.x < 32) {
            float v = 0.f;
            #pragma unroll
            for (int hh = 0; hh < H; hh++) v += sred[hh * 32 + threadIdx.x];
            out[(size_t)n * 32 + threadIdx.x] = v * (1.0f / H);
        }
    }
}

// ---------------- launch ----------------

extern "C" void kernel_launch(void* const* d_in, const int* in_sizes, int n_in,
                              void* d_out, int out_size, void* d_ws, size_t ws_size,
                              hipStream_t stream) {
    const float* x    = (const float*)d_in[0];
    const int*   src  = (const int*)d_in[1];
    const int*   dst  = (const int*)d_in[2];
    const float* W1   = (const float*)d_in[3];
    const float* al1  = (const float*)d_in[4];
    const float* ar1  = (const float*)d_in[5];
    const float* b1   = (const float*)d_in[6];
    const float* W2   = (const float*)d_in[7];
    const float* al2  = (const float*)d_in[8];
    const float* ar2  = (const float*)d_in[9];
    const float* b2   = (const float*)d_in[10];
    const float* W3   = (const float*)d_in[11];
    const float* al3  = (const float*)d_in[12];
    const float* ar3  = (const float*)d_in[13];
    const float* b3   = (const float*)d_in[14];
    const float* resW3= (const float*)d_in[15];
    float* out = (float*)d_out;

    const int N = in_sizes[0] / 128;
    const int E = in_sizes[1];

    // workspace layout (fp32 elements)
    float* fws  = (float*)d_ws;
    float* feat = fws;                          // N*192 (layers 1-2 use first N*128)
    float* h1v  = feat + (size_t)N * 192;       // N*128
    float* h2v  = h1v + (size_t)N * 128;        // N*128
    float* res3 = h2v + (size_t)N * 128;        // N*192
    float* elb  = res3 + (size_t)N * 192;       // N*6
    float* erb  = elb + (size_t)N * 6;          // N*6
    int* deg       = (int*)(erb + (size_t)N * 6);  // N
    int* row_start = deg + N;                      // N+1
    int* csr_src   = row_start + (N + 1);          // E

    // ---- CSR build (by dst) ----
    hipMemsetAsync(deg, 0, (size_t)N * sizeof(int), stream);
    hist_kernel<<<dim3((E + 255) / 256), dim3(256), 0, stream>>>(dst, E, deg);
    scan_kernel<<<dim3(1), dim3(1024), 0, stream>>>(deg, row_start, N);
    hipMemsetAsync(deg, 0, (size_t)N * sizeof(int), stream);
    fill_kernel<<<dim3((E + 255) / 256), dim3(256), 0, stream>>>(src, dst, E, row_start, deg, csr_src);

    const int ROWS = 4;
    dim3 gemm_grid((N + ROWS - 1) / ROWS);

    // ---- Layer 1: x -> h1 (H=4, relu, no residual) ----
    fc_att<128, 4, false, ROWS><<<gemm_grid, dim3(128), 0, stream>>>(
        x, W1, nullptr, al1, ar1, feat, nullptr, elb, erb, N);
    gat_agg<4, true, false><<<dim3(N), dim3(256), 0, stream>>>(
        feat, elb, erb, row_start, csr_src, b1, nullptr, h1v, N);

    // ---- Layer 2: h1 -> h2 (H=4, relu, identity residual) ----
    fc_att<128, 4, false, ROWS><<<gemm_grid, dim3(128), 0, stream>>>(
        h1v, W2, nullptr, al2, ar2, feat, nullptr, elb, erb, N);
    gat_agg<4, true, false><<<dim3(N), dim3(256), 0, stream>>>(
        feat, elb, erb, row_start, csr_src, b2, h1v, h2v, N);

    // ---- Layer 3: h2 -> out (H=6, no relu, projected residual, head-mean) ----
    fc_att<192, 6, true, ROWS><<<gemm_grid, dim3(384), 0, stream>>>(
        h2v, W3, resW3, al3, ar3, feat, res3, elb, erb, N);
    gat_agg<6, false, true><<<dim3(N), dim3(384), 0, stream>>>(
        feat, elb, erb, row_start, csr_src, b3, res3, out, N);
}

// Round 2
// 765.602 us; speedup vs baseline: 1.6194x; 1.6194x over previous
//
#include <hip/hip_runtime.h>
#include <math.h>

// GAT 3-layer forward on MI355X. fp32 throughout.
// N=50000 nodes, E=850000 edges (incl self loops), IN=128, HID=OUT=32, HEADS=(4,4,6).

// ---------------- CSR build (by dst) ----------------

__global__ void hist_kernel(const int* __restrict__ dst, int E, int* __restrict__ deg) {
    int i = blockIdx.x * blockDim.x + threadIdx.x;
    if (i < E) atomicAdd(&deg[dst[i]], 1);
}

__global__ void scan_kernel(const int* __restrict__ deg, int* __restrict__ row_start, int n) {
    const int T = 1024;
    __shared__ int sums[T];
    int t = threadIdx.x;
    int chunk = (n + T - 1) / T;
    int begin = t * chunk;
    int finish = begin + chunk; if (finish > n) finish = n;
    int s = 0;
    for (int i = begin; i < finish; i++) s += deg[i];
    sums[t] = s;
    __syncthreads();
    for (int off = 1; off < T; off <<= 1) {
        int u = (t >= off) ? sums[t - off] : 0;
        __syncthreads();
        sums[t] += u;
        __syncthreads();
    }
    int base = (t == 0) ? 0 : sums[t - 1];
    for (int i = begin; i < finish; i++) { row_start[i] = base; base += deg[i]; }
    if (t == T - 1) row_start[n] = sums[T - 1];
}

__global__ void fill_kernel(const int* __restrict__ src, const int* __restrict__ dst, int E,
                            const int* __restrict__ row_start, int* __restrict__ cursor,
                            int* __restrict__ csr_src) {
    int i = blockIdx.x * blockDim.x + threadIdx.x;
    if (i < E) {
        int d = dst[i];
        int pos = atomicAdd(&cursor[d], 1);
        csr_src[row_start[d] + pos] = src[i];
    }
}

// ---------------- fc + attention logits ----------------

template <int M1, int H, bool RES, int ROWS>
__global__ void fc_att(const float* __restrict__ h, const float* __restrict__ W,
                       const float* __restrict__ Wres, const float* __restrict__ al,
                       const float* __restrict__ ar, float* __restrict__ feat,
                       float* __restrict__ res_out, float* __restrict__ el,
                       float* __restrict__ er, int N) {
    __shared__ float hrow[ROWS][128];
    int n0 = blockIdx.x * ROWS;
    int t = threadIdx.x;

    for (int i = t; i < ROWS * 128; i += blockDim.x) {
        int r = i >> 7, c = i & 127;
        int nn = n0 + r;
        hrow[r][c] = (nn < N) ? h[(size_t)nn * 128 + c] : 0.f;
    }
    __syncthreads();

    if (t < M1) {
        float acc[ROWS];
        #pragma unroll
        for (int r = 0; r < ROWS; r++) acc[r] = 0.f;
        #pragma unroll 8
        for (int k = 0; k < 128; k++) {
            float w = W[(size_t)k * M1 + t];
            #pragma unroll
            for (int r = 0; r < ROWS; r++) acc[r] += hrow[r][k] * w;
        }
        float alv = al[t], arv = ar[t];
        #pragma unroll
        for (int r = 0; r < ROWS; r++) {
            int nn = n0 + r;
            if (nn >= N) continue;
            feat[(size_t)nn * M1 + t] = acc[r];
            float pl = acc[r] * alv;
            float pr = acc[r] * arv;
            #pragma unroll
            for (int off = 1; off < 32; off <<= 1) {
                pl += __shfl_xor(pl, off);
                pr += __shfl_xor(pr, off);
            }
            if ((t & 31) == 0) {
                el[(size_t)nn * H + (t >> 5)] = pl;
                er[(size_t)nn * H + (t >> 5)] = pr;
            }
        }
    } else if (RES) {
        int j = t - M1;  // < 192
        float acc[ROWS];
        #pragma unroll
        for (int r = 0; r < ROWS; r++) acc[r] = 0.f;
        #pragma unroll 8
        for (int k = 0; k < 128; k++) {
            float w = Wres[(size_t)k * 192 + j];
            #pragma unroll
            for (int r = 0; r < ROWS; r++) acc[r] += hrow[r][k] * w;
        }
        #pragma unroll
        for (int r = 0; r < ROWS; r++) {
            int nn = n0 + r;
            if (nn < N) res_out[(size_t)nn * 192 + j] = acc[r];
        }
    }
}

// ---------------- single-pass per-node edge softmax + aggregate ----------------
// One block per node, ONE THREAD PER OUTPUT DIM (t in [0, H*32)).
// Per chunk of <=128 edges: stage src ids in LDS, compute all logits once
// (coalesced el gathers), per-head online-softmax max/denom, then a weighted
// accumulation loop where each edge's full feat row is read coalesced and
// 4 edges' gathers are kept in flight per thread.

template <int H, bool RELU, bool MEAN>
__global__ void gat_agg(const float* __restrict__ feat, const float* __restrict__ el,
                        const float* __restrict__ er, const int* __restrict__ row_start,
                        const int* __restrict__ csr_src, const float* __restrict__ bias,
                        const float* __restrict__ residual, float* __restrict__ out, int N) {
    constexpr int ROW = H * 32;
    constexpr int CHUNK = 128;
    __shared__ int   s_src[CHUNK];
    __shared__ float s_w[CHUNK][H];
    __shared__ float s_er[H], s_m[H], s_d[H], s_scale[H];
    __shared__ float s_red[MEAN ? ROW : 1];

    int n = blockIdx.x;
    int t = threadIdx.x;       // output dim: h*32 + d
    int h = t >> 5;

    int start = row_start[n];
    int end   = row_start[n + 1];

    if (t < H) {
        s_er[t] = er[(size_t)n * H + t];
        s_m[t]  = -INFINITY;
        s_d[t]  = 0.f;
    }
    __syncthreads();

    float acc = 0.f;
    for (int cs = start; cs < end; cs += CHUNK) {
        int c = end - cs; if (c > CHUNK) c = CHUNK;

        for (int i = t; i < c; i += ROW) s_src[i] = csr_src[cs + i];
        __syncthreads();

        // logits: coalesced — consecutive threads hit consecutive el addresses
        for (int i = t; i < c * H; i += ROW) {
            int j = i / H, hh = i - j * H;
            float e = el[(size_t)s_src[j] * H + hh] + s_er[hh];
            s_w[j][hh] = (e >= 0.f) ? e : 0.2f * e;
        }
        __syncthreads();

        // per-head online max + denom (thread h owns head h; c is small)
        if (t < H) {
            float mold = s_m[t];
            float mnew = mold;
            for (int j = 0; j < c; j++) mnew = fmaxf(mnew, s_w[j][t]);
            float sc = __expf(mold - mnew);   // first chunk: exp(-inf)=0
            float d = s_d[t] * sc;
            for (int j = 0; j < c; j++) {
                float w = __expf(s_w[j][t] - mnew);
                s_w[j][t] = w;
                d += w;
            }
            s_m[t] = mnew; s_d[t] = d; s_scale[t] = sc;
        }
        __syncthreads();

        acc *= s_scale[h];

        int j = 0;
        for (; j + 4 <= c; j += 4) {
            int s0 = s_src[j], s1 = s_src[j+1], s2 = s_src[j+2], s3 = s_src[j+3];
            float f0 = feat[(size_t)s0 * ROW + t];
            float f1 = feat[(size_t)s1 * ROW + t];
            float f2 = feat[(size_t)s2 * ROW + t];
            float f3 = feat[(size_t)s3 * ROW + t];
            acc += s_w[j][h] * f0 + s_w[j+1][h] * f1 + s_w[j+2][h] * f2 + s_w[j+3][h] * f3;
        }
        for (; j < c; j++) acc += s_w[j][h] * feat[(size_t)s_src[j] * ROW + t];
        __syncthreads();   // protect s_src/s_w before next chunk
    }

    float rst = acc / fmaxf(s_d[h], 1e-9f);
    rst += bias[t];
    if (residual) rst += residual[(size_t)n * ROW + t];
    if (RELU) rst = fmaxf(rst, 0.f);

    if (!MEAN) {
        out[(size_t)n * ROW + t] = rst;
    } else {
        s_red[t] = rst;
        __syncthreads();
        if (t < 32) {
            float v = 0.f;
            #pragma unroll
            for (int hh = 0; hh < H; hh++) v += s_red[hh * 32 + t];
            out[(size_t)n * 32 + t] = v * (1.0f / H);
        }
    }
}

// ---------------- launch ----------------

extern "C" void kernel_launch(void* const* d_in, const int* in_sizes, int n_in,
                              void* d_out, int out_size, void* d_ws, size_t ws_size,
                              hipStream_t stream) {
    const float* x    = (const float*)d_in[0];
    const int*   src  = (const int*)d_in[1];
    const int*   dst  = (const int*)d_in[2];
    const float* W1   = (const float*)d_in[3];
    const float* al1  = (const float*)d_in[4];
    const float* ar1  = (const float*)d_in[5];
    const float* b1   = (const float*)d_in[6];
    const float* W2   = (const float*)d_in[7];
    const float* al2  = (const float*)d_in[8];
    const float* ar2  = (const float*)d_in[9];
    const float* b2   = (const float*)d_in[10];
    const float* W3   = (const float*)d_in[11];
    const float* al3  = (const float*)d_in[12];
    const float* ar3  = (const float*)d_in[13];
    const float* b3   = (const float*)d_in[14];
    const float* resW3= (const float*)d_in[15];
    float* out = (float*)d_out;

    const int N = in_sizes[0] / 128;
    const int E = in_sizes[1];

    // workspace layout (fp32 elements)
    float* fws  = (float*)d_ws;
    float* feat = fws;                          // N*192 (layers 1-2 use first N*128)
    float* h1v  = feat + (size_t)N * 192;       // N*128
    float* h2v  = h1v + (size_t)N * 128;        // N*128
    float* res3 = h2v + (size_t)N * 128;        // N*192
    float* elb  = res3 + (size_t)N * 192;       // N*6
    float* erb  = elb + (size_t)N * 6;          // N*6
    int* deg       = (int*)(erb + (size_t)N * 6);  // N
    int* row_start = deg + N;                      // N+1
    int* csr_src   = row_start + (N + 1);          // E

    // ---- CSR build (by dst) ----
    hipMemsetAsync(deg, 0, (size_t)N * sizeof(int), stream);
    hist_kernel<<<dim3((E + 255) / 256), dim3(256), 0, stream>>>(dst, E, deg);
    scan_kernel<<<dim3(1), dim3(1024), 0, stream>>>(deg, row_start, N);
    hipMemsetAsync(deg, 0, (size_t)N * sizeof(int), stream);
    fill_kernel<<<dim3((E + 255) / 256), dim3(256), 0, stream>>>(src, dst, E, row_start, deg, csr_src);

    const int ROWS = 4;
    dim3 gemm_grid((N + ROWS - 1) / ROWS);

    // ---- Layer 1: x -> h1 (H=4, relu, no residual) ----
    fc_att<128, 4, false, ROWS><<<gemm_grid, dim3(128), 0, stream>>>(
        x, W1, nullptr, al1, ar1, feat, nullptr, elb, erb, N);
    gat_agg<4, true, false><<<dim3(N), dim3(128), 0, stream>>>(
        feat, elb, erb, row_start, csr_src, b1, nullptr, h1v, N);

    // ---- Layer 2: h1 -> h2 (H=4, relu, identity residual) ----
    fc_att<128, 4, false, ROWS><<<gemm_grid, dim3(128), 0, stream>>>(
        h1v, W2, nullptr, al2, ar2, feat, nullptr, elb, erb, N);
    gat_agg<4, true, false><<<dim3(N), dim3(128), 0, stream>>>(
        feat, elb, erb, row_start, csr_src, b2, h1v, h2v, N);

    // ---- Layer 3: h2 -> out (H=6, no relu, projected residual, head-mean) ----
    fc_att<192, 6, true, ROWS><<<gemm_grid, dim3(384), 0, stream>>>(
        h2v, W3, resW3, al3, ar3, feat, res3, elb, erb, N);
    gat_agg<6, false, true><<<dim3(N), dim3(192), 0, stream>>>(
        feat, elb, erb, row_start, csr_src, b3, res3, out, N);
}

// Round 3
// 752.927 us; speedup vs baseline: 1.6466x; 1.0168x over previous
//
#include <hip/hip_runtime.h>
#include <math.h>

// GAT 3-layer forward on MI355X.
// N=50000 nodes, E=850000 edges (incl self loops), IN=128, HID=OUT=32, HEADS=(4,4,6).
// GEMMs via split-f16 MFMA (hi/lo, 3 mfma per tile) — near-fp32 accuracy at matrix-core rate.

typedef _Float16 v8h __attribute__((ext_vector_type(8)));
typedef float f32x4 __attribute__((ext_vector_type(4)));

// ---------------- CSR build (by dst) ----------------

__global__ void hist_kernel(const int* __restrict__ dst, int E, int* __restrict__ deg) {
    int i = blockIdx.x * blockDim.x + threadIdx.x;
    if (i < E) atomicAdd(&deg[dst[i]], 1);
}

__global__ void scan_kernel(const int* __restrict__ deg, int* __restrict__ row_start, int n) {
    const int T = 1024;
    __shared__ int sums[T];
    int t = threadIdx.x;
    int chunk = (n + T - 1) / T;
    int begin = t * chunk;
    int finish = begin + chunk; if (finish > n) finish = n;
    int s = 0;
    for (int i = begin; i < finish; i++) s += deg[i];
    sums[t] = s;
    __syncthreads();
    for (int off = 1; off < T; off <<= 1) {
        int u = (t >= off) ? sums[t - off] : 0;
        __syncthreads();
        sums[t] += u;
        __syncthreads();
    }
    int base = (t == 0) ? 0 : sums[t - 1];
    for (int i = begin; i < finish; i++) { row_start[i] = base; base += deg[i]; }
    if (t == T - 1) row_start[n] = sums[T - 1];
}

__global__ void fill_kernel(const int* __restrict__ src, const int* __restrict__ dst, int E,
                            const int* __restrict__ row_start, int* __restrict__ cursor,
                            int* __restrict__ csr_src) {
    int i = blockIdx.x * blockDim.x + threadIdx.x;
    if (i < E) {
        int d = dst[i];
        int pos = atomicAdd(&cursor[d], 1);
        csr_src[row_start[d] + pos] = src[i];
    }
}

// ---------------- weight transpose + f16 hi/lo split (once per call) ----------------
// Output layout (f16 elements, n-major [C][128]):
//   W1h@0, W1l@16384, W2h@32768, W2l@49152, W3h@65536, W3l@90112, Wrh@114688, Wrl@139264

__global__ void wsplit_all(const float* __restrict__ W1, const float* __restrict__ W2,
                           const float* __restrict__ W3, const float* __restrict__ Wr,
                           _Float16* __restrict__ o) {
    int i = blockIdx.x * blockDim.x + threadIdx.x;
    if (i >= 81920) return;
    const float* W; int C; int ohi; int e;
    if (i < 16384)      { W = W1; C = 128; ohi = 0;      e = i; }
    else if (i < 32768) { W = W2; C = 128; ohi = 32768;  e = i - 16384; }
    else if (i < 57344) { W = W3; C = 192; ohi = 65536;  e = i - 32768; }
    else                { W = Wr; C = 192; ohi = 114688; e = i - 57344; }
    int c = e >> 7, k = e & 127;
    float v = W[(size_t)k * C + c];
    _Float16 hv = (_Float16)v;
    o[ohi + e] = hv;
    o[ohi + C * 128 + e] = (_Float16)(v - (float)hv);
}

// ---------------- MFMA fc (+ attention logits) ----------------
// Block: 256 threads = 4 waves; M-tile 64 rows (16/wave); all CC output cols.
// A (h rows) staged fp32->f16 hi/lo in padded LDS; B from pre-split n-major Wt.
// D = A*B via 3 mfma_f32_16x16x32_f16 (lo*hi + hi*lo + hi*hi).
// Epilogue: write feat; if ATT, per-head el/er via 16-lane cross-lane reduce.

template <int CC, int H, bool ATT>
__global__ __launch_bounds__(256) void mfma_fc(
    const float* __restrict__ hsrc,
    const _Float16* __restrict__ Bhi, const _Float16* __restrict__ Blo,
    const float* __restrict__ al, const float* __restrict__ ar,
    float* __restrict__ outp, int out_stride,
    float* __restrict__ el, float* __restrict__ er, int N) {
    constexpr int TILES = CC / 16;
    constexpr int AST = 128 + 8;   // padded LDS row stride (f16 elems): 272B -> ~2-way (free)
    __shared__ _Float16 a_hi[64 * AST];
    __shared__ _Float16 a_lo[64 * AST];

    int m0 = blockIdx.x * 64;
    int t = threadIdx.x;

    // stage A: 64 rows x 128 cols, convert to hi/lo f16
    for (int i = t; i < 64 * 32; i += 256) {
        int r = i >> 5;
        int c4 = (i & 31) << 2;
        float4 v = make_float4(0.f, 0.f, 0.f, 0.f);
        int m = m0 + r;
        if (m < N) v = *(const float4*)(hsrc + (size_t)m * 128 + c4);
        _Float16* ph = a_hi + r * AST + c4;
        _Float16* pl = a_lo + r * AST + c4;
        float vv[4] = {v.x, v.y, v.z, v.w};
        #pragma unroll
        for (int q = 0; q < 4; q++) {
            _Float16 hh = (_Float16)vv[q];
            ph[q] = hh;
            pl[q] = (_Float16)(vv[q] - (float)hh);
        }
    }
    __syncthreads();

    int wave = t >> 6;
    int lane = t & 63;
    int ln = lane & 15;
    int quad = lane >> 4;

    f32x4 acc[TILES];
    #pragma unroll
    for (int i = 0; i < TILES; i++) acc[i] = (f32x4){0.f, 0.f, 0.f, 0.f};

    const _Float16* arow_h = a_hi + (wave * 16 + ln) * AST;
    const _Float16* arow_l = a_lo + (wave * 16 + ln) * AST;

    #pragma unroll
    for (int k0 = 0; k0 < 128; k0 += 32) {
        v8h ah = *(const v8h*)(arow_h + k0 + quad * 8);
        v8h alo = *(const v8h*)(arow_l + k0 + quad * 8);
        #pragma unroll
        for (int tt = 0; tt < TILES; tt++) {
            size_t boff = (size_t)(tt * 16 + ln) * 128 + k0 + quad * 8;
            v8h bh = *(const v8h*)(Bhi + boff);
            v8h bl = *(const v8h*)(Blo + boff);
            acc[tt] = __builtin_amdgcn_mfma_f32_16x16x32_f16(alo, bh, acc[tt], 0, 0, 0);
            acc[tt] = __builtin_amdgcn_mfma_f32_16x16x32_f16(ah, bl, acc[tt], 0, 0, 0);
            acc[tt] = __builtin_amdgcn_mfma_f32_16x16x32_f16(ah, bh, acc[tt], 0, 0, 0);
        }
    }

    // epilogue: C/D layout col=lane&15, row=quad*4+reg
    #pragma unroll
    for (int tt = 0; tt < TILES; tt++) {
        int n = tt * 16 + ln;
        #pragma unroll
        for (int r = 0; r < 4; r++) {
            int m = m0 + wave * 16 + quad * 4 + r;
            if (m < N) outp[(size_t)m * out_stride + n] = acc[tt][r];
        }
    }
    if constexpr (ATT) {
        #pragma unroll
        for (int hg = 0; hg < H; hg++) {
            float a0 = al[hg * 32 + ln], a1 = al[hg * 32 + 16 + ln];
            float r0 = ar[hg * 32 + ln], r1 = ar[hg * 32 + 16 + ln];
            #pragma unroll
            for (int r = 0; r < 4; r++) {
                float pl = acc[2 * hg][r] * a0 + acc[2 * hg + 1][r] * a1;
                float pr = acc[2 * hg][r] * r0 + acc[2 * hg + 1][r] * r1;
                #pragma unroll
                for (int off = 1; off < 16; off <<= 1) {
                    pl += __shfl_xor(pl, off);
                    pr += __shfl_xor(pr, off);
                }
                int m = m0 + wave * 16 + quad * 4 + r;
                if (ln == 0 && m < N) {
                    el[(size_t)m * H + hg] = pl;
                    er[(size_t)m * H + hg] = pr;
                }
            }
        }
    }
}

// ---------------- single-pass per-node edge softmax + aggregate ----------------

template <int H, bool RELU, bool MEAN>
__global__ void gat_agg(const float* __restrict__ feat, const float* __restrict__ el,
                        const float* __restrict__ er, const int* __restrict__ row_start,
                        const int* __restrict__ csr_src, const float* __restrict__ bias,
                        const float* __restrict__ residual, float* __restrict__ out, int N) {
    constexpr int ROW = H * 32;
    constexpr int CHUNK = 128;
    __shared__ int   s_src[CHUNK];
    __shared__ float s_w[CHUNK][H];
    __shared__ float s_er[H], s_m[H], s_d[H], s_scale[H];
    __shared__ float s_red[MEAN ? ROW : 1];

    int n = blockIdx.x;
    int t = threadIdx.x;       // output dim: h*32 + d
    int h = t >> 5;

    int start = row_start[n];
    int end   = row_start[n + 1];

    if (t < H) {
        s_er[t] = er[(size_t)n * H + t];
        s_m[t]  = -INFINITY;
        s_d[t]  = 0.f;
    }
    __syncthreads();

    float acc = 0.f;
    for (int cs = start; cs < end; cs += CHUNK) {
        int c = end - cs; if (c > CHUNK) c = CHUNK;

        for (int i = t; i < c; i += ROW) s_src[i] = csr_src[cs + i];
        __syncthreads();

        for (int i = t; i < c * H; i += ROW) {
            int j = i / H, hh = i - j * H;
            float e = el[(size_t)s_src[j] * H + hh] + s_er[hh];
            s_w[j][hh] = (e >= 0.f) ? e : 0.2f * e;
        }
        __syncthreads();

        if (t < H) {
            float mold = s_m[t];
            float mnew = mold;
            for (int j = 0; j < c; j++) mnew = fmaxf(mnew, s_w[j][t]);
            float sc = __expf(mold - mnew);
            float d = s_d[t] * sc;
            for (int j = 0; j < c; j++) {
                float w = __expf(s_w[j][t] - mnew);
                s_w[j][t] = w;
                d += w;
            }
            s_m[t] = mnew; s_d[t] = d; s_scale[t] = sc;
        }
        __syncthreads();

        acc *= s_scale[h];

        int j = 0;
        for (; j + 4 <= c; j += 4) {
            int s0 = s_src[j], s1 = s_src[j+1], s2 = s_src[j+2], s3 = s_src[j+3];
            float f0 = feat[(size_t)s0 * ROW + t];
            float f1 = feat[(size_t)s1 * ROW + t];
            float f2 = feat[(size_t)s2 * ROW + t];
            float f3 = feat[(size_t)s3 * ROW + t];
            acc += s_w[j][h] * f0 + s_w[j+1][h] * f1 + s_w[j+2][h] * f2 + s_w[j+3][h] * f3;
        }
        for (; j < c; j++) acc += s_w[j][h] * feat[(size_t)s_src[j] * ROW + t];
        __syncthreads();
    }

    float rst = acc / fmaxf(s_d[h], 1e-9f);
    rst += bias[t];
    if (residual) rst += residual[(size_t)n * ROW + t];
    if (RELU) rst = fmaxf(rst, 0.f);

    if (!MEAN) {
        out[(size_t)n * ROW + t] = rst;
    } else {
        s_red[t] = rst;
        __syncthreads();
        if (t < 32) {
            float v = 0.f;
            #pragma unroll
            for (int hh = 0; hh < H; hh++) v += s_red[hh * 32 + t];
            out[(size_t)n * 32 + t] = v * (1.0f / H);
        }
    }
}

// ---------------- launch ----------------

extern "C" void kernel_launch(void* const* d_in, const int* in_sizes, int n_in,
                              void* d_out, int out_size, void* d_ws, size_t ws_size,
                              hipStream_t stream) {
    const float* x    = (const float*)d_in[0];
    const int*   src  = (const int*)d_in[1];
    const int*   dst  = (const int*)d_in[2];
    const float* W1   = (const float*)d_in[3];
    const float* al1  = (const float*)d_in[4];
    const float* ar1  = (const float*)d_in[5];
    const float* b1   = (const float*)d_in[6];
    const float* W2   = (const float*)d_in[7];
    const float* al2  = (const float*)d_in[8];
    const float* ar2  = (const float*)d_in[9];
    const float* b2   = (const float*)d_in[10];
    const float* W3   = (const float*)d_in[11];
    const float* al3  = (const float*)d_in[12];
    const float* ar3  = (const float*)d_in[13];
    const float* b3   = (const float*)d_in[14];
    const float* resW3= (const float*)d_in[15];
    float* out = (float*)d_out;

    const int N = in_sizes[0] / 128;
    const int E = in_sizes[1];

    // workspace layout
    float* fws  = (float*)d_ws;
    float* feat = fws;                          // N*192 (layers 1-2 use first N*128)
    float* h1v  = feat + (size_t)N * 192;       // N*128
    float* h2v  = h1v + (size_t)N * 128;        // N*128
    float* res3 = h2v + (size_t)N * 128;        // N*192
    float* elb  = res3 + (size_t)N * 192;       // N*6
    float* erb  = elb + (size_t)N * 6;          // N*6
    _Float16* wts = (_Float16*)(erb + (size_t)N * 6);  // 163840 f16
    int* deg       = (int*)(wts + 163840);         // N
    int* row_start = deg + N;                      // N+1
    int* csr_src   = row_start + (N + 1);          // E

    const _Float16* W1h = wts;
    const _Float16* W1l = wts + 16384;
    const _Float16* W2h = wts + 32768;
    const _Float16* W2l = wts + 49152;
    const _Float16* W3h = wts + 65536;
    const _Float16* W3l = wts + 90112;
    const _Float16* Wrh = wts + 114688;
    const _Float16* Wrl = wts + 139264;

    // ---- CSR build (by dst) + weight split ----
    hipMemsetAsync(deg, 0, (size_t)N * sizeof(int), stream);
    hist_kernel<<<dim3((E + 255) / 256), dim3(256), 0, stream>>>(dst, E, deg);
    scan_kernel<<<dim3(1), dim3(1024), 0, stream>>>(deg, row_start, N);
    hipMemsetAsync(deg, 0, (size_t)N * sizeof(int), stream);
    fill_kernel<<<dim3((E + 255) / 256), dim3(256), 0, stream>>>(src, dst, E, row_start, deg, csr_src);
    wsplit_all<<<dim3(320), dim3(256), 0, stream>>>(W1, W2, W3, resW3, wts);

    dim3 mb((N + 63) / 64);

    // ---- Layer 1 ----
    mfma_fc<128, 4, true><<<mb, dim3(256), 0, stream>>>(
        x, W1h, W1l, al1, ar1, feat, 128, elb, erb, N);
    gat_agg<4, true, false><<<dim3(N), dim3(128), 0, stream>>>(
        feat, elb, erb, row_start, csr_src, b1, nullptr, h1v, N);

    // ---- Layer 2 ----
    mfma_fc<128, 4, true><<<mb, dim3(256), 0, stream>>>(
        h1v, W2h, W2l, al2, ar2, feat, 128, elb, erb, N);
    gat_agg<4, true, false><<<dim3(N), dim3(128), 0, stream>>>(
        feat, elb, erb, row_start, csr_src, b2, h1v, h2v, N);

    // ---- Layer 3 ----
    mfma_fc<192, 6, true><<<mb, dim3(256), 0, stream>>>(
        h2v, W3h, W3l, al3, ar3, feat, 192, elb, erb, N);
    mfma_fc<192, 1, false><<<mb, dim3(256), 0, stream>>>(
        h2v, Wrh, Wrl, nullptr, nullptr, res3, 192, nullptr, nullptr, N);
    gat_agg<6, false, true><<<dim3(N), dim3(192), 0, stream>>>(
        feat, elb, erb, row_start, csr_src, b3, res3, out, N);
}